// Round 2
// baseline (11974.924 us; speedup 1.0000x reference)
//
#include <hip/hip_runtime.h>
#include <cstdint>
#include <cstddef>

// ---------------- problem constants ----------------
constexpr int Nn  = 200000;
constexpr int Ee  = 1600000;
constexpr int EPp = 1000000;

// ---------------- small kernels ----------------

__global__ __launch_bounds__(256) void k_deg(const int* __restrict__ dst,
                                             float* __restrict__ rdeg, int E) {
  int i = blockIdx.x * 256 + threadIdx.x;
  if (i < E) atomicAdd(&rdeg[dst[i]], 1.0f);
}

__global__ __launch_bounds__(256) void k_rdeg(float* rdeg, int n) {
  int i = blockIdx.x * 256 + threadIdx.x;
  if (i < n) rdeg[i] = 1.0f / fmaxf(rdeg[i], 1.0f);
}

// Stack Wl[l] (64x64) on top of Wr[l] (64x64) -> Wcat[l] (128x64)
__global__ __launch_bounds__(256) void k_wcat(const float* __restrict__ Wl,
                                              const float* __restrict__ Wr,
                                              float* __restrict__ Wcat) {
  for (int i = blockIdx.x * 256 + threadIdx.x; i < 3 * 64 * 64; i += gridDim.x * 256) {
    int l = i >> 12, r = i & 4095, k = r >> 6, d = r & 63;
    Wcat[l * 8192 + k * 64 + d]        = Wl[i];
    Wcat[l * 8192 + (k + 64) * 64 + d] = Wr[i];
  }
}

// scatter-add x[src]*rdeg[dst] into agg[dst]; 16 threads (of 4 floats) per edge
__global__ __launch_bounds__(256) void k_scatter(const float* __restrict__ x, int ldx,
                                                 const int* __restrict__ src,
                                                 const int* __restrict__ dst,
                                                 const float* __restrict__ rdeg,
                                                 float* __restrict__ agg, int E) {
  int gid = blockIdx.x * 256 + threadIdx.x;
  int e = gid >> 4, c = gid & 15;
  if (e >= E) return;
  int s = src[e], d = dst[e];
  float4 v = *(const float4*)(x + (size_t)s * ldx + c * 4);
  float r = rdeg[d];
  float* a = agg + (size_t)d * 64 + c * 4;
  atomicAdd(a + 0, v.x * r);
  atomicAdd(a + 1, v.y * r);
  atomicAdd(a + 2, v.z * r);
  atomicAdd(a + 3, v.w * r);
}

// column sums of h [n,64]: stats[0:64]=sum, stats[64:128]=sum of squares
__global__ __launch_bounds__(256) void k_stats(const float* __restrict__ h,
                                               float* __restrict__ stats, int n) {
  int lane = threadIdx.x & 63, grp = threadIdx.x >> 6;
  float s = 0.f, s2 = 0.f;
  for (int r = blockIdx.x * 4 + grp; r < n; r += gridDim.x * 4) {
    float v = h[(size_t)r * 64 + lane];
    s += v; s2 += v * v;
  }
  __shared__ float l1[4][64], l2[4][64];
  l1[grp][lane] = s; l2[grp][lane] = s2;
  __syncthreads();
  if (grp == 0) {
    s  = l1[0][lane] + l1[1][lane] + l1[2][lane] + l1[3][lane];
    s2 = l2[0][lane] + l2[1][lane] + l2[2][lane] + l2[3][lane];
    atomicAdd(&stats[lane], s);
    atomicAdd(&stats[64 + lane], s2);
  }
}

// stats -> msmean (stats[128:192]) and inv std (stats[192:256])
__global__ void k_statfin(float* stats, const float* __restrict__ ms_, int n) {
  int d = threadIdx.x;
  if (d < 64) {
    float invn = 1.0f / (float)n;
    float m  = stats[d] * invn;
    float e2 = stats[64 + d] * invn;
    float ms = ms_[d];
    float var = e2 - (2.0f * ms - ms * ms) * m * m;
    stats[128 + d] = ms * m;
    stats[192 + d] = rsqrtf(var + 1e-5f);
  }
}

// graph_norm apply + residual; write into z column (row stride 192)
__global__ __launch_bounds__(256) void k_norm(const float* __restrict__ h,
                                              const float* __restrict__ stats,
                                              const float* __restrict__ w,
                                              const float* __restrict__ b,
                                              float* __restrict__ zcol,
                                              const float* __restrict__ prev, int n) {
  int i = blockIdx.x * 256 + threadIdx.x;
  if (i >= n * 64) return;
  int r = i >> 6, d = i & 63;
  float v = (h[i] - stats[128 + d]) * stats[192 + d] * w[d] + b[d];
  if (prev) v += prev[(size_t)r * 192 + d];
  zcol[(size_t)r * 192 + d] = v;
}

// zn = normalize(dyt2(zn) + x_res) rows of 64; one wave per row
__global__ __launch_bounds__(256) void k_rownorm(float* __restrict__ zn,
                                                 const float* __restrict__ xres,
                                                 const float* __restrict__ w,
                                                 const float* __restrict__ b,
                                                 const float* __restrict__ a_, int n) {
  int i = blockIdx.x * 256 + threadIdx.x;
  if (i >= n * 64) return;
  int d = i & 63;
  float al = a_[0];
  float v = w[d] * tanhf(al * zn[i]) + b[d] + xres[i];
  float s = v * v;
  #pragma unroll
  for (int o = 32; o; o >>= 1) s += __shfl_xor(s, o, 64);
  zn[i] = v / (sqrtf(s) + 1e-10f);
}

// log_softmax over 20 classes -> out
__global__ __launch_bounds__(256) void k_lsm(const float* __restrict__ in,
                                             float* __restrict__ out, int n) {
  int r = blockIdx.x * 256 + threadIdx.x;
  if (r >= n) return;
  const float* p = in + (size_t)r * 20;
  float m = -1e30f;
  #pragma unroll
  for (int j = 0; j < 20; ++j) m = fmaxf(m, p[j]);
  float s = 0.f;
  #pragma unroll
  for (int j = 0; j < 20; ++j) s += expf(p[j] - m);
  float ls = logf(s) + m;
  float* q = out + (size_t)r * 20;
  #pragma unroll
  for (int j = 0; j < 20; ++j) q[j] = p[j] - ls;
}

// c3: dot(h_row[128], w) + b -> sigmoid
__global__ __launch_bounds__(256) void k_c3(const float* __restrict__ h,
                                            const float* __restrict__ w,
                                            const float* __restrict__ b,
                                            float* __restrict__ out, int n) {
  __shared__ float ws_[128];
  if (threadIdx.x < 128) ws_[threadIdx.x] = w[threadIdx.x];
  __syncthreads();
  int e = blockIdx.x * 256 + threadIdx.x;
  if (e >= n) return;
  const float4* p = (const float4*)(h + (size_t)e * 128);
  float s = b[0];
  #pragma unroll
  for (int j = 0; j < 32; ++j) {
    float4 v = p[j];
    s += v.x * ws_[4 * j] + v.y * ws_[4 * j + 1] + v.z * ws_[4 * j + 2] + v.w * ws_[4 * j + 3];
  }
  out[e] = 1.0f / (1.0f + expf(-s));
}

// ---------------- generic fused fp32 GEMM ----------------
// C[M,O] = act( concat-A[M,K] @ W[K,O] + bias )
//   A element for k<K1 comes from A1 (row idx1[m] if idx1 else m, stride lda1),
//   for k>=K1 from A2 similarly. Optional DynamicTanh on A load.
//   act: 0 none, 1 exact gelu.
#define BKC 16
__global__ __launch_bounds__(256) void fgemm(
    const float* __restrict__ A1, int lda1,
    const float* __restrict__ A2, int lda2, int K1,
    const int* __restrict__ idx1, const int* __restrict__ idx2,
    const float* __restrict__ dytw, const float* __restrict__ dytb,
    const float* __restrict__ dyta,
    const float* __restrict__ W, const float* __restrict__ bias,
    float* __restrict__ C, int ldc,
    int M, int K, int O, int act) {
  __shared__ float As[BKC][68];
  __shared__ float Ws[BKC][68];
  int tid = threadIdx.x;
  int bm = blockIdx.x, bo = blockIdx.y;
  int tx = tid & 15, ty = tid >> 4;

  float acc[4][4] = {{0.f, 0.f, 0.f, 0.f}, {0.f, 0.f, 0.f, 0.f},
                     {0.f, 0.f, 0.f, 0.f}, {0.f, 0.f, 0.f, 0.f}};
  float alpha = dytw ? dyta[0] : 0.f;

  // A staging: thread loads 4 consecutive k of one row
  int m_l = tid >> 2;            // 0..63
  int kk0 = (tid & 3) * 4;       // 0,4,8,12
  int gm_row = bm * 64 + m_l;
  if (gm_row >= M) gm_row = M - 1;
  const float* rowp1 = A1 + (size_t)(idx1 ? idx1[gm_row] : gm_row) * lda1;
  const float* rowp2 = A2 ? (A2 + (size_t)(idx2 ? idx2[gm_row] : gm_row) * lda2) : nullptr;

  // W staging: thread loads 4 consecutive o of one k-row
  int kw = tid >> 4;             // 0..15
  int o_l = (tid & 15) * 4;      // 0..60

  for (int k0 = 0; k0 < K; k0 += BKC) {
    #pragma unroll
    for (int j = 0; j < 4; ++j) {
      int k = k0 + kk0 + j;
      float v = (k < K1) ? rowp1[k] : rowp2[k - K1];
      if (dytw) v = dytw[k] * tanhf(alpha * v) + dytb[k];
      As[kk0 + j][m_l] = v;
    }
    {
      int k = k0 + kw;
      #pragma unroll
      for (int j = 0; j < 4; ++j) {
        int o = bo * 64 + o_l + j;
        Ws[kw][o_l + j] = (o < O) ? W[(size_t)k * O + o] : 0.f;
      }
    }
    __syncthreads();
    #pragma unroll
    for (int k = 0; k < BKC; ++k) {
      float4 a = *(const float4*)&As[k][tx * 4];
      float4 w = *(const float4*)&Ws[k][ty * 4];
      float av[4] = {a.x, a.y, a.z, a.w};
      float wv[4] = {w.x, w.y, w.z, w.w};
      #pragma unroll
      for (int i2 = 0; i2 < 4; ++i2)
        #pragma unroll
        for (int j2 = 0; j2 < 4; ++j2) acc[i2][j2] += av[i2] * wv[j2];
    }
    __syncthreads();
  }

  #pragma unroll
  for (int i2 = 0; i2 < 4; ++i2) {
    int m = bm * 64 + tx * 4 + i2;
    if (m >= M) continue;
    #pragma unroll
    for (int j2 = 0; j2 < 4; ++j2) {
      int o = bo * 64 + ty * 4 + j2;
      if (o >= O) continue;
      float v = acc[i2][j2] + (bias ? bias[o] : 0.f);
      if (act == 1) v = 0.5f * v * (1.0f + erff(v * 0.70710678118654752f));
      C[(size_t)m * ldc + o] = v;
    }
  }
}

static inline void gemm(hipStream_t st,
                        const float* A1, int lda1, const float* A2, int lda2, int K1,
                        const int* i1, const int* i2,
                        const float* dw, const float* db, const float* da,
                        const float* W, const float* bias,
                        float* C, int ldc, int M, int K, int O, int act) {
  dim3 g((unsigned)((M + 63) / 64), (unsigned)((O + 63) / 64));
  fgemm<<<g, 256, 0, st>>>(A1, lda1, A2, lda2, K1, i1, i2, dw, db, da, W, bias, C, ldc, M, K, O, act);
}

// ---------------- launcher ----------------
extern "C" void kernel_launch(void* const* d_in, const int* in_sizes, int n_in,
                              void* d_out, int out_size, void* d_ws, size_t ws_size,
                              hipStream_t stream) {
  const float* x_res  = (const float*)d_in[0];
  const float* Wl     = (const float*)d_in[1];
  const float* bl     = (const float*)d_in[2];
  const float* Wr     = (const float*)d_in[3];
  const float* gn_w   = (const float*)d_in[4];
  const float* gn_b   = (const float*)d_in[5];
  const float* gn_ms  = (const float*)d_in[6];
  const float* dyt1_w = (const float*)d_in[7];
  const float* dyt1_b = (const float*)d_in[8];
  const float* dyt1_a = (const float*)d_in[9];
  const float* lin1_w = (const float*)d_in[10];
  const float* lin1_b = (const float*)d_in[11];
  const float* lin2_w = (const float*)d_in[12];
  const float* lin2_b = (const float*)d_in[13];
  const float* lin3_w = (const float*)d_in[14];
  const float* lin3_b = (const float*)d_in[15];
  const float* dyt2_w = (const float*)d_in[16];
  const float* dyt2_b = (const float*)d_in[17];
  const float* dyt2_a = (const float*)d_in[18];
  const float* adyt1_w = (const float*)d_in[19];
  const float* adyt1_b = (const float*)d_in[20];
  const float* adyt1_a = (const float*)d_in[21];
  const float* aa1_w  = (const float*)d_in[22];
  const float* aa1_b  = (const float*)d_in[23];
  const float* aa2_w  = (const float*)d_in[24];
  const float* aa2_b  = (const float*)d_in[25];
  const float* aa3_w  = (const float*)d_in[26];
  const float* aa3_b  = (const float*)d_in[27];
  const float* adyt2_w = (const float*)d_in[28];
  const float* adyt2_b = (const float*)d_in[29];
  const float* adyt2_a = (const float*)d_in[30];
  const float* aa4_w  = (const float*)d_in[31];
  const float* aa4_b  = (const float*)d_in[32];
  const float* c1_w   = (const float*)d_in[33];
  const float* c1_b   = (const float*)d_in[34];
  const float* c2_w   = (const float*)d_in[35];
  const float* c2_b   = (const float*)d_in[36];
  const float* c3_w   = (const float*)d_in[37];
  const float* c3_b   = (const float*)d_in[38];
  const int*   edge   = (const int*)d_in[39];     // [2,E]
  const int*   contact = (const int*)d_in[40];    // [2,EP]

  const size_t N = (size_t)Nn;
  const size_t ws_floats = ws_size / 4;

  // ---- dynamic workspace layout (floats) ----
  // persistent: rdeg(N) | z(192N) | zn(64N) | Wcat(24576) | stats(256) | pool...
  float* ws    = (float*)d_ws;
  float* rdeg  = ws;
  float* z     = rdeg + N;
  float* zn    = z + 192 * N;           // doubles as h during GNN phase
  float* Wcat  = zn + 64 * N;
  float* stats = Wcat + 3 * 128 * 64;
  float* pool  = stats + 256;
  const size_t persist = (size_t)(pool - ws);
  if (ws_floats < persist + 64 * N) return;  // can't even fit agg: bail cleanly
  const size_t pool_floats = ws_floats - persist;

  // degree -> reciprocal clamped degree
  hipMemsetAsync(rdeg, 0, N * sizeof(float), stream);
  k_deg<<<(Ee + 255) / 256, 256, 0, stream>>>(edge + Ee, rdeg, Ee);
  k_rdeg<<<(Nn + 255) / 256, 256, 0, stream>>>(rdeg, Nn);
  k_wcat<<<48, 256, 0, stream>>>(Wl, Wr, Wcat);

  // ---- GNN phase: agg lives in the pool, h lives in zn's slot ----
  float* agg = pool;   // [N,64]
  float* h   = zn;     // [N,64]
  for (int l = 0; l < 3; ++l) {
    const float* xi = (l == 0) ? x_res : (z + (size_t)(l - 1) * 64);
    int ldx = (l == 0) ? 64 : 192;
    hipMemsetAsync(agg, 0, N * 64 * sizeof(float), stream);
    hipMemsetAsync(stats, 0, 128 * sizeof(float), stream);
    k_scatter<<<(Ee * 16) / 256, 256, 0, stream>>>(xi, ldx, edge, edge + Ee, rdeg, agg, Ee);
    gemm(stream, agg, 64, xi, ldx, 64, nullptr, nullptr,
         nullptr, nullptr, nullptr,
         Wcat + (size_t)l * 8192, bl + l * 64, h, 64, Nn, 128, 64, 1);
    k_stats<<<1024, 256, 0, stream>>>(h, stats, Nn);
    k_statfin<<<1, 64, 0, stream>>>(stats, gn_ms + l * 64, Nn);
    k_norm<<<(Nn * 64) / 256, 256, 0, stream>>>(h, stats, gn_w + l * 64, gn_b + l * 64,
                                                z + (size_t)l * 64,
                                                (l > 0) ? (z + (size_t)(l - 1) * 64) : nullptr, Nn);
  }

  // ---- node-chunked MLP + annotation head (all row-local) ----
  size_t nc_max = (pool_floats / (2 * 256)) & ~(size_t)63;  // rows per chunk, x64
  if (nc_max > N) nc_max = N;
  for (size_t r0 = 0; r0 < N; r0 += nc_max) {
    int nc = (int)((N - r0 < nc_max) ? (N - r0) : nc_max);
    float* bufA = pool;
    float* bufB = pool + (size_t)nc_max * 256;
    const float* zrow = z + r0 * 192;
    float* znrow = zn + r0 * 64;
    const float* xrow = x_res + r0 * 64;
    // MLP: dyt1 -> 256 -> 256 -> 64
    gemm(stream, zrow, 192, nullptr, 0, 192, nullptr, nullptr,
         dyt1_w, dyt1_b, dyt1_a, lin1_w, lin1_b, bufA, 256, nc, 192, 256, 1);
    gemm(stream, bufA, 256, nullptr, 0, 256, nullptr, nullptr,
         nullptr, nullptr, nullptr, lin2_w, lin2_b, bufB, 256, nc, 256, 256, 1);
    gemm(stream, bufB, 256, nullptr, 0, 256, nullptr, nullptr,
         nullptr, nullptr, nullptr, lin3_w, lin3_b, znrow, 64, nc, 256, 64, 1);
    int grid_rn = (nc * 64 + 255) / 256;
    k_rownorm<<<grid_rn, 256, 0, stream>>>(znrow, xrow, dyt2_w, dyt2_b, dyt2_a, nc);
    // annotation head: [x_res, zn] -> 256 -> 256 -> 256 -> 20 -> log_softmax
    gemm(stream, xrow, 64, znrow, 64, 64, nullptr, nullptr,
         adyt1_w, adyt1_b, adyt1_a, aa1_w, aa1_b, bufA, 256, nc, 128, 256, 1);
    gemm(stream, bufA, 256, nullptr, 0, 256, nullptr, nullptr,
         nullptr, nullptr, nullptr, aa2_w, aa2_b, bufB, 256, nc, 256, 256, 1);
    gemm(stream, bufB, 256, nullptr, 0, 256, nullptr, nullptr,
         nullptr, nullptr, nullptr, aa3_w, aa3_b, bufA, 256, nc, 256, 256, 1);
    gemm(stream, bufA, 256, nullptr, 0, 256, nullptr, nullptr,
         adyt2_w, adyt2_b, adyt2_a, aa4_w, aa4_b, bufB, 20, nc, 256, 20, 0);
    k_lsm<<<(nc + 255) / 256, 256, 0, stream>>>(bufB, (float*)d_out + r0 * 20, nc);
  }

  // ---- edge head in chunks: [zn[ci], zn[cj]] -> 128 -> 128 -> 1 -> sigmoid ----
  const int* ci = contact;
  const int* cj = contact + EPp;
  float* eout = (float*)d_out + (size_t)Nn * 20;
  size_t ce_max = (pool_floats / (2 * 128)) & ~(size_t)63;
  if (ce_max > (size_t)EPp) ce_max = EPp;
  for (size_t done = 0; done < (size_t)EPp; done += ce_max) {
    int ce = (int)(((size_t)EPp - done < ce_max) ? ((size_t)EPp - done) : ce_max);
    float* bufA = pool;
    float* bufB = pool + ce_max * 128;
    gemm(stream, zn, 64, zn, 64, 64, ci + done, cj + done,
         nullptr, nullptr, nullptr, c1_w, c1_b, bufA, 128, ce, 128, 128, 1);
    gemm(stream, bufA, 128, nullptr, 0, 128, nullptr, nullptr,
         nullptr, nullptr, nullptr, c2_w, c2_b, bufB, 128, ce, 128, 128, 1);
    k_c3<<<(ce + 255) / 256, 256, 0, stream>>>(bufB, c3_w, c3_b, eout + done, ce);
  }
}

// Round 3
// 4997.467 us; speedup vs baseline: 2.3962x; 2.3962x over previous
//
#include <hip/hip_runtime.h>
#include <cstdint>
#include <cstddef>

// ---------------- problem constants ----------------
constexpr int Nn  = 200000;
constexpr int Ee  = 1600000;
constexpr int EPp = 1000000;

typedef __attribute__((ext_vector_type(8))) short bf8_t;
typedef __attribute__((ext_vector_type(4))) float f4_t;

__device__ inline unsigned short f2bf(float f) {
  union { float f; unsigned u; } v; v.f = f;
  unsigned r = v.u + 0x7FFFu + ((v.u >> 16) & 1u);
  return (unsigned short)(r >> 16);
}
__device__ inline float bf2f(unsigned short u) {
  union { unsigned u; float f; } v; v.u = ((unsigned)u) << 16;
  return v.f;
}
__device__ inline float gelu_f(float v) {
  return 0.5f * v * (1.0f + erff(v * 0.70710678118654752f));
}

// ---------------- degree / CSR build ----------------

__global__ __launch_bounds__(256) void k_degi(const int* __restrict__ dst,
                                              int* __restrict__ cnt, int E) {
  int i = blockIdx.x * 256 + threadIdx.x;
  if (i < E) atomicAdd(&cnt[dst[i]], 1);
}

__global__ __launch_bounds__(256) void k_rdeg(const int* __restrict__ cnt,
                                              float* __restrict__ rdeg, int n) {
  int i = blockIdx.x * 256 + threadIdx.x;
  if (i < n) rdeg[i] = 1.0f / (float)(cnt[i] > 1 ? cnt[i] : 1);
}

// scan pass 1: per-1024-chunk exclusive scan, block totals to bsum
__global__ __launch_bounds__(256) void k_scan1(const int* __restrict__ in,
                                               int* __restrict__ out,
                                               int* __restrict__ bsum, int n) {
  __shared__ int sd[256];
  int t = threadIdx.x;
  int base = blockIdx.x * 1024 + t * 4;
  int v[4]; int ts = 0;
  #pragma unroll
  for (int j = 0; j < 4; ++j) { v[j] = (base + j < n) ? in[base + j] : 0; ts += v[j]; }
  sd[t] = ts; __syncthreads();
  for (int off = 1; off < 256; off <<= 1) {
    int x = (t >= off) ? sd[t - off] : 0;
    __syncthreads();
    sd[t] += x;
    __syncthreads();
  }
  int excl = sd[t] - ts;
  #pragma unroll
  for (int j = 0; j < 4; ++j) { if (base + j < n) out[base + j] = excl; excl += v[j]; }
  if (t == 255) bsum[blockIdx.x] = sd[255];
}

__global__ void k_scan2(int* bsum, int nb) {  // single block of 256
  __shared__ int sd[256];
  int t = threadIdx.x;
  int v = (t < nb) ? bsum[t] : 0;
  sd[t] = v; __syncthreads();
  for (int off = 1; off < 256; off <<= 1) {
    int x = (t >= off) ? sd[t - off] : 0;
    __syncthreads();
    sd[t] += x;
    __syncthreads();
  }
  if (t < nb) bsum[t] = sd[t] - v;  // exclusive block offsets
}

__global__ __launch_bounds__(256) void k_scan3(const int* __restrict__ part,
                                               const int* __restrict__ bsum,
                                               int* __restrict__ rowptr,
                                               int* __restrict__ cursor,
                                               int n, int total) {
  int i = blockIdx.x * 256 + threadIdx.x;
  if (i == 0) rowptr[n] = total;
  if (i < n) { int v = part[i] + bsum[i >> 10]; rowptr[i] = v; cursor[i] = v; }
}

__global__ __launch_bounds__(256) void k_fill(const int* __restrict__ src,
                                              const int* __restrict__ dst,
                                              int* __restrict__ cursor,
                                              int* __restrict__ colidx, int E) {
  int e = blockIdx.x * 256 + threadIdx.x;
  if (e >= E) return;
  int pos = atomicAdd(&cursor[dst[e]], 1);
  colidx[pos] = src[e];
}

// gather-mean: one wave per node, 4 groups of 16 lanes
__global__ __launch_bounds__(256) void k_gather(const float* __restrict__ x, int ldx,
                                                const int* __restrict__ rowptr,
                                                const int* __restrict__ colidx,
                                                const float* __restrict__ rdeg,
                                                float* __restrict__ agg, int n) {
  int wave = threadIdx.x >> 6, lane = threadIdx.x & 63;
  int node = blockIdx.x * 4 + wave;
  if (node >= n) return;
  int grp = lane >> 4, c = (lane & 15) * 4;
  int r0 = rowptr[node], r1 = rowptr[node + 1];
  float sx = 0.f, sy = 0.f, sz = 0.f, sw = 0.f;
  for (int j = r0 + grp; j < r1; j += 4) {
    const float4 v = *(const float4*)(x + (size_t)colidx[j] * ldx + c);
    sx += v.x; sy += v.y; sz += v.z; sw += v.w;
  }
  sx += __shfl_xor(sx, 16, 64); sx += __shfl_xor(sx, 32, 64);
  sy += __shfl_xor(sy, 16, 64); sy += __shfl_xor(sy, 32, 64);
  sz += __shfl_xor(sz, 16, 64); sz += __shfl_xor(sz, 32, 64);
  sw += __shfl_xor(sw, 16, 64); sw += __shfl_xor(sw, 32, 64);
  if (grp == 0) {
    float r = rdeg[node];
    float4 o; o.x = sx * r; o.y = sy * r; o.z = sz * r; o.w = sw * r;
    *(float4*)(agg + (size_t)node * 64 + c) = o;
  }
}

// ---------------- misc small kernels ----------------

__global__ __launch_bounds__(256) void k_wcat(const float* __restrict__ Wl,
                                              const float* __restrict__ Wr,
                                              float* __restrict__ Wcat) {
  for (int i = blockIdx.x * 256 + threadIdx.x; i < 3 * 64 * 64; i += gridDim.x * 256) {
    int l = i >> 12, r = i & 4095, k = r >> 6, d = r & 63;
    Wcat[l * 8192 + k * 64 + d]        = Wl[i];
    Wcat[l * 8192 + (k + 64) * 64 + d] = Wr[i];
  }
}

// transpose + cvt weights: W[K][N] fp32 -> Wt[Npad][K] bf16 (zero-fill n>=N)
__global__ __launch_bounds__(256) void k_wt(const float* __restrict__ W,
                                            unsigned short* __restrict__ Wt,
                                            int K, int kshift, int N, int total) {
  int i = blockIdx.x * 256 + threadIdx.x;
  if (i >= total) return;
  int n = i >> kshift, k = i & (K - 1);
  float v = (n < N) ? W[(size_t)k * N + n] : 0.f;
  Wt[i] = f2bf(v);
}

__global__ __launch_bounds__(256) void k_stats(const float* __restrict__ h,
                                               float* __restrict__ stats, int n) {
  int lane = threadIdx.x & 63, grp = threadIdx.x >> 6;
  float s = 0.f, s2 = 0.f;
  for (int r = blockIdx.x * 4 + grp; r < n; r += gridDim.x * 4) {
    float v = h[(size_t)r * 64 + lane];
    s += v; s2 += v * v;
  }
  __shared__ float l1[4][64], l2[4][64];
  l1[grp][lane] = s; l2[grp][lane] = s2;
  __syncthreads();
  if (grp == 0) {
    s  = l1[0][lane] + l1[1][lane] + l1[2][lane] + l1[3][lane];
    s2 = l2[0][lane] + l2[1][lane] + l2[2][lane] + l2[3][lane];
    atomicAdd(&stats[lane], s);
    atomicAdd(&stats[64 + lane], s2);
  }
}

__global__ void k_statfin(float* stats, const float* __restrict__ ms_, int n) {
  int d = threadIdx.x;
  if (d < 64) {
    float invn = 1.0f / (float)n;
    float m  = stats[d] * invn;
    float e2 = stats[64 + d] * invn;
    float ms = ms_[d];
    float var = e2 - (2.0f * ms - ms * ms) * m * m;
    stats[128 + d] = ms * m;
    stats[192 + d] = rsqrtf(var + 1e-5f);
  }
}

__global__ __launch_bounds__(256) void k_norm(const float* __restrict__ h,
                                              const float* __restrict__ stats,
                                              const float* __restrict__ w,
                                              const float* __restrict__ b,
                                              float* __restrict__ zcol,
                                              const float* __restrict__ prev, int n) {
  int i = blockIdx.x * 256 + threadIdx.x;
  if (i >= n * 64) return;
  int r = i >> 6, d = i & 63;
  float v = (h[i] - stats[128 + d]) * stats[192 + d] * w[d] + b[d];
  if (prev) v += prev[(size_t)r * 192 + d];
  zcol[(size_t)r * 192 + d] = v;
}

__global__ __launch_bounds__(256) void k_rownorm(float* __restrict__ zn,
                                                 const float* __restrict__ xres,
                                                 const float* __restrict__ w,
                                                 const float* __restrict__ b,
                                                 const float* __restrict__ a_, int n) {
  int i = blockIdx.x * 256 + threadIdx.x;
  if (i >= n * 64) return;
  int d = i & 63;
  float al = a_[0];
  float v = w[d] * tanhf(al * zn[i]) + b[d] + xres[i];
  float s = v * v;
  #pragma unroll
  for (int o = 32; o; o >>= 1) s += __shfl_xor(s, o, 64);
  zn[i] = v / (sqrtf(s) + 1e-10f);
}

// log_softmax over 20 classes, input stride ld
__global__ __launch_bounds__(256) void k_lsm(const float* __restrict__ in, int ld,
                                             float* __restrict__ out, int n) {
  int r = blockIdx.x * 256 + threadIdx.x;
  if (r >= n) return;
  const float* p = in + (size_t)r * ld;
  float m = -1e30f;
  #pragma unroll
  for (int j = 0; j < 20; ++j) m = fmaxf(m, p[j]);
  float s = 0.f;
  #pragma unroll
  for (int j = 0; j < 20; ++j) s += expf(p[j] - m);
  float ls = logf(s) + m;
  float* q = out + (size_t)r * 20;
  #pragma unroll
  for (int j = 0; j < 20; ++j) q[j] = p[j] - ls;
}

// ---------------- fp32 trunk GEMM (unchanged) ----------------
#define BKC 16
__global__ __launch_bounds__(256) void fgemm(
    const float* __restrict__ A1, int lda1,
    const float* __restrict__ A2, int lda2, int K1,
    const float* __restrict__ dytw, const float* __restrict__ dytb,
    const float* __restrict__ dyta,
    const float* __restrict__ W, const float* __restrict__ bias,
    float* __restrict__ C, int ldc,
    int M, int K, int O, int act) {
  __shared__ float As[BKC][68];
  __shared__ float Ws[BKC][68];
  int tid = threadIdx.x;
  int bm = blockIdx.x, bo = blockIdx.y;
  int tx = tid & 15, ty = tid >> 4;

  float acc[4][4] = {{0.f,0.f,0.f,0.f},{0.f,0.f,0.f,0.f},{0.f,0.f,0.f,0.f},{0.f,0.f,0.f,0.f}};
  float alpha = dytw ? dyta[0] : 0.f;

  int m_l = tid >> 2;
  int kk0 = (tid & 3) * 4;
  int gm_row = bm * 64 + m_l;
  if (gm_row >= M) gm_row = M - 1;
  const float* rowp1 = A1 + (size_t)gm_row * lda1;
  const float* rowp2 = A2 ? (A2 + (size_t)gm_row * lda2) : nullptr;

  int kw = tid >> 4;
  int o_l = (tid & 15) * 4;

  for (int k0 = 0; k0 < K; k0 += BKC) {
    #pragma unroll
    for (int j = 0; j < 4; ++j) {
      int k = k0 + kk0 + j;
      float v = (k < K1) ? rowp1[k] : rowp2[k - K1];
      if (dytw) v = dytw[k] * tanhf(alpha * v) + dytb[k];
      As[kk0 + j][m_l] = v;
    }
    {
      int k = k0 + kw;
      #pragma unroll
      for (int j = 0; j < 4; ++j) {
        int o = bo * 64 + o_l + j;
        Ws[kw][o_l + j] = (o < O) ? W[(size_t)k * O + o] : 0.f;
      }
    }
    __syncthreads();
    #pragma unroll
    for (int k = 0; k < BKC; ++k) {
      float4 a = *(const float4*)&As[k][tx * 4];
      float4 w = *(const float4*)&Ws[k][ty * 4];
      float av[4] = {a.x, a.y, a.z, a.w};
      float wv[4] = {w.x, w.y, w.z, w.w};
      #pragma unroll
      for (int i2 = 0; i2 < 4; ++i2)
        #pragma unroll
        for (int j2 = 0; j2 < 4; ++j2) acc[i2][j2] += av[i2] * wv[j2];
    }
    __syncthreads();
  }

  #pragma unroll
  for (int i2 = 0; i2 < 4; ++i2) {
    int m = bm * 64 + tx * 4 + i2;
    if (m >= M) continue;
    #pragma unroll
    for (int j2 = 0; j2 < 4; ++j2) {
      int o = bo * 64 + ty * 4 + j2;
      if (o >= O) continue;
      float v = acc[i2][j2] + (bias ? bias[o] : 0.f);
      if (act == 1) v = gelu_f(v);
      C[(size_t)m * ldc + o] = v;
    }
  }
}

static inline void gemm(hipStream_t st,
                        const float* A1, int lda1, const float* A2, int lda2, int K1,
                        const float* dw, const float* db, const float* da,
                        const float* W, const float* bias,
                        float* C, int ldc, int M, int K, int O, int act) {
  dim3 g((unsigned)((M + 63) / 64), (unsigned)((O + 63) / 64));
  fgemm<<<g, 256, 0, st>>>(A1, lda1, A2, lda2, K1, dw, db, da, W, bias, C, ldc, M, K, O, act);
}

// ---------------- generic bf16 MFMA GEMM (barrier-free) ----------------
// C = act( concatA[M,K] @ Wt^T + bias ); Wt is [Npad][K] bf16 (n-major).
// A fp32 or bf16 (a_bf16), optional DynamicTanh on load. Block: 256thr/4 waves,
// 128 rows per block, NT n-tiles of 16 per block-col (grid.y covers Npad).
template <int NT>
__global__ __launch_bounds__(256) void mgemm(
    const void* __restrict__ A1, int lda1,
    const void* __restrict__ A2, int lda2, int K1, int a_bf16,
    const float* __restrict__ dytw, const float* __restrict__ dytb,
    const float* __restrict__ dyta,
    const unsigned short* __restrict__ Wt,
    const float* __restrict__ bias,
    void* __restrict__ Cout, int ldc, int c_bf16, int act,
    int M, int K, int N) {
  int lane = threadIdx.x & 63, wave = threadIdx.x >> 6;
  int quad = lane >> 4, col = lane & 15;
  int row0 = blockIdx.x * 128 + wave * 32;
  int n_base = blockIdx.y * NT * 16;

  f4_t acc[2][NT];
  #pragma unroll
  for (int mt = 0; mt < 2; ++mt)
    #pragma unroll
    for (int nt = 0; nt < NT; ++nt) acc[mt][nt] = (f4_t)0.f;

  int gm[2];
  gm[0] = row0 + col;      if (gm[0] >= M) gm[0] = M - 1;
  gm[1] = row0 + 16 + col; if (gm[1] >= M) gm[1] = M - 1;
  float alpha = dytw ? dyta[0] : 0.f;

  for (int kc0 = 0; kc0 < K; kc0 += 32) {
    int kc = kc0 + quad * 8;
    union { bf8_t v; unsigned short u[8]; } a[2];
    #pragma unroll
    for (int mt = 0; mt < 2; ++mt) {
      const void* src; size_t off;
      if (kc < K1) { src = A1; off = (size_t)gm[mt] * lda1 + kc; }
      else         { src = A2; off = (size_t)gm[mt] * lda2 + kc - K1; }
      if (a_bf16) {
        bf8_t raw = *(const bf8_t*)((const unsigned short*)src + off);
        a[mt].v = raw;
        if (dytw) {
          #pragma unroll
          for (int j = 0; j < 8; ++j) {
            float f = bf2f((unsigned short)a[mt].u[j]);
            f = dytw[kc + j] * tanhf(alpha * f) + dytb[kc + j];
            a[mt].u[j] = f2bf(f);
          }
        }
      } else {
        const float* p = (const float*)src + off;
        float4 f0 = *(const float4*)p;
        float4 f1 = *(const float4*)(p + 4);
        float ff[8] = {f0.x, f0.y, f0.z, f0.w, f1.x, f1.y, f1.z, f1.w};
        if (dytw) {
          #pragma unroll
          for (int j = 0; j < 8; ++j)
            ff[j] = dytw[kc + j] * tanhf(alpha * ff[j]) + dytb[kc + j];
        }
        #pragma unroll
        for (int j = 0; j < 8; ++j) a[mt].u[j] = f2bf(ff[j]);
      }
    }
    #pragma unroll
    for (int nt = 0; nt < NT; ++nt) {
      bf8_t b = *(const bf8_t*)(Wt + (size_t)(n_base + nt * 16 + col) * K + kc);
      acc[0][nt] = __builtin_amdgcn_mfma_f32_16x16x32_bf16(a[0].v, b, acc[0][nt], 0, 0, 0);
      acc[1][nt] = __builtin_amdgcn_mfma_f32_16x16x32_bf16(a[1].v, b, acc[1][nt], 0, 0, 0);
    }
  }

  #pragma unroll
  for (int nt = 0; nt < NT; ++nt) {
    int n = n_base + nt * 16 + col;
    float bs = (bias && n < N) ? bias[n] : 0.f;
    #pragma unroll
    for (int mt = 0; mt < 2; ++mt)
      #pragma unroll
      for (int r = 0; r < 4; ++r) {
        int row = row0 + mt * 16 + quad * 4 + r;
        if (row >= M || n >= N) continue;
        float v = acc[mt][nt][r] + bs;
        if (act) v = gelu_f(v);
        if (c_bf16) ((unsigned short*)Cout)[(size_t)row * ldc + n] = f2bf(v);
        else        ((float*)Cout)[(size_t)row * ldc + n] = v;
      }
  }
}

// ---------------- fused edge head: c1+c2+c3+sigmoid ----------------
// per block: 128 contact rows; A = [zn[ci],zn[cj]] gathered to registers.
__global__ __launch_bounds__(256) void k_edge(
    const float* __restrict__ zn,
    const int* __restrict__ ci, const int* __restrict__ cj,
    const unsigned short* __restrict__ w1t, const float* __restrict__ b1,
    const unsigned short* __restrict__ w2t, const float* __restrict__ b2,
    const float* __restrict__ w3, const float* __restrict__ b3,
    float* __restrict__ out, int M) {
  __shared__ unsigned short h1[4][32][136];  // per-wave private region
  int lane = threadIdx.x & 63, wave = threadIdx.x >> 6;
  int quad = lane >> 4, col = lane & 15;
  int row0 = blockIdx.x * 128 + wave * 32;

  f4_t acc[2][8];
  #pragma unroll
  for (int mt = 0; mt < 2; ++mt)
    #pragma unroll
    for (int nt = 0; nt < 8; ++nt) acc[mt][nt] = (f4_t)0.f;

  const float* ap[2][2];
  #pragma unroll
  for (int mt = 0; mt < 2; ++mt) {
    int r = row0 + mt * 16 + col;
    if (r >= M) r = M - 1;
    ap[mt][0] = zn + (size_t)ci[r] * 64;
    ap[mt][1] = zn + (size_t)cj[r] * 64;
  }

  // ---- c1 ----
  #pragma unroll
  for (int s = 0; s < 4; ++s) {
    int half = s >> 1;
    int kc = (s & 1) * 32 + quad * 8;     // offset within the 64-float half
    int kf = s * 32 + quad * 8;           // full-K offset (for W)
    union { bf8_t v; unsigned short u[8]; } a[2];
    #pragma unroll
    for (int mt = 0; mt < 2; ++mt) {
      const float* p = ap[mt][half] + kc;
      float4 f0 = *(const float4*)p;
      float4 f1 = *(const float4*)(p + 4);
      float ff[8] = {f0.x, f0.y, f0.z, f0.w, f1.x, f1.y, f1.z, f1.w};
      #pragma unroll
      for (int j = 0; j < 8; ++j) a[mt].u[j] = f2bf(ff[j]);
    }
    #pragma unroll
    for (int nt = 0; nt < 8; ++nt) {
      bf8_t b = *(const bf8_t*)(w1t + (size_t)(nt * 16 + col) * 128 + kf);
      acc[0][nt] = __builtin_amdgcn_mfma_f32_16x16x32_bf16(a[0].v, b, acc[0][nt], 0, 0, 0);
      acc[1][nt] = __builtin_amdgcn_mfma_f32_16x16x32_bf16(a[1].v, b, acc[1][nt], 0, 0, 0);
    }
  }

  // bias + gelu -> h1 (LDS, bf16), then layout hop C/D -> A
  #pragma unroll
  for (int nt = 0; nt < 8; ++nt) {
    float bs = b1[nt * 16 + col];
    #pragma unroll
    for (int mt = 0; mt < 2; ++mt)
      #pragma unroll
      for (int r = 0; r < 4; ++r) {
        float v = gelu_f(acc[mt][nt][r] + bs);
        h1[wave][mt * 16 + quad * 4 + r][nt * 16 + col] = f2bf(v);
      }
  }
  __syncthreads();

  // ---- c2 (+ fused c3 dot) ----
  #pragma unroll
  for (int mt = 0; mt < 2; ++mt)
    #pragma unroll
    for (int nt = 0; nt < 8; ++nt) acc[mt][nt] = (f4_t)0.f;

  #pragma unroll
  for (int s = 0; s < 4; ++s) {
    int kc = s * 32 + quad * 8;
    bf8_t a0 = *(const bf8_t*)&h1[wave][col][kc];
    bf8_t a1 = *(const bf8_t*)&h1[wave][16 + col][kc];
    #pragma unroll
    for (int nt = 0; nt < 8; ++nt) {
      bf8_t b = *(const bf8_t*)(w2t + (size_t)(nt * 16 + col) * 128 + kc);
      acc[0][nt] = __builtin_amdgcn_mfma_f32_16x16x32_bf16(a0, b, acc[0][nt], 0, 0, 0);
      acc[1][nt] = __builtin_amdgcn_mfma_f32_16x16x32_bf16(a1, b, acc[1][nt], 0, 0, 0);
    }
  }

  float p[2][4] = {{0.f,0.f,0.f,0.f},{0.f,0.f,0.f,0.f}};
  #pragma unroll
  for (int nt = 0; nt < 8; ++nt) {
    float bs = b2[nt * 16 + col];
    float wv = w3[nt * 16 + col];
    #pragma unroll
    for (int mt = 0; mt < 2; ++mt)
      #pragma unroll
      for (int r = 0; r < 4; ++r)
        p[mt][r] += gelu_f(acc[mt][nt][r] + bs) * wv;
  }
  float b3v = b3[0];
  #pragma unroll
  for (int mt = 0; mt < 2; ++mt)
    #pragma unroll
    for (int r = 0; r < 4; ++r) {
      float s = p[mt][r];
      s += __shfl_xor(s, 1, 64);
      s += __shfl_xor(s, 2, 64);
      s += __shfl_xor(s, 4, 64);
      s += __shfl_xor(s, 8, 64);
      p[mt][r] = s;
    }
  if (col == 0) {
    #pragma unroll
    for (int mt = 0; mt < 2; ++mt)
      #pragma unroll
      for (int r = 0; r < 4; ++r) {
        int row = row0 + mt * 16 + quad * 4 + r;
        if (row < M) out[row] = 1.0f / (1.0f + expf(-(p[mt][r] + b3v)));
      }
  }
}

// ---------------- launcher ----------------
extern "C" void kernel_launch(void* const* d_in, const int* in_sizes, int n_in,
                              void* d_out, int out_size, void* d_ws, size_t ws_size,
                              hipStream_t stream) {
  const float* x_res  = (const float*)d_in[0];
  const float* Wl     = (const float*)d_in[1];
  const float* bl     = (const float*)d_in[2];
  const float* Wr     = (const float*)d_in[3];
  const float* gn_w   = (const float*)d_in[4];
  const float* gn_b   = (const float*)d_in[5];
  const float* gn_ms  = (const float*)d_in[6];
  const float* dyt1_w = (const float*)d_in[7];
  const float* dyt1_b = (const float*)d_in[8];
  const float* dyt1_a = (const float*)d_in[9];
  const float* lin1_w = (const float*)d_in[10];
  const float* lin1_b = (const float*)d_in[11];
  const float* lin2_w = (const float*)d_in[12];
  const float* lin2_b = (const float*)d_in[13];
  const float* lin3_w = (const float*)d_in[14];
  const float* lin3_b = (const float*)d_in[15];
  const float* dyt2_w = (const float*)d_in[16];
  const float* dyt2_b = (const float*)d_in[17];
  const float* dyt2_a = (const float*)d_in[18];
  const float* adyt1_w = (const float*)d_in[19];
  const float* adyt1_b = (const float*)d_in[20];
  const float* adyt1_a = (const float*)d_in[21];
  const float* aa1_w  = (const float*)d_in[22];
  const float* aa1_b  = (const float*)d_in[23];
  const float* aa2_w  = (const float*)d_in[24];
  const float* aa2_b  = (const float*)d_in[25];
  const float* aa3_w  = (const float*)d_in[26];
  const float* aa3_b  = (const float*)d_in[27];
  const float* adyt2_w = (const float*)d_in[28];
  const float* adyt2_b = (const float*)d_in[29];
  const float* adyt2_a = (const float*)d_in[30];
  const float* aa4_w  = (const float*)d_in[31];
  const float* aa4_b  = (const float*)d_in[32];
  const float* c1_w   = (const float*)d_in[33];
  const float* c1_b   = (const float*)d_in[34];
  const float* c2_w   = (const float*)d_in[35];
  const float* c2_b   = (const float*)d_in[36];
  const float* c3_w   = (const float*)d_in[37];
  const float* c3_b   = (const float*)d_in[38];
  const int*   edge   = (const int*)d_in[39];
  const int*   contact = (const int*)d_in[40];

  const size_t N = (size_t)Nn;
  const size_t ws_floats = ws_size / 4;

  // persistent region
  float* ws    = (float*)d_ws;
  float* rdeg  = ws;                         // N
  float* z     = rdeg + N;                   // 192N
  float* zn    = z + 192 * N;                // 64N (h during GNN)
  float* Wcat  = zn + 64 * N;                // 24576
  float* stats = Wcat + 3 * 128 * 64;        // 256
  unsigned short* wt_c1  = (unsigned short*)(stats + 256);   // 128*128
  unsigned short* wt_c2  = wt_c1 + 128 * 128;                // 128*128
  unsigned short* wt_aa1 = wt_c2 + 128 * 128;                // 256*128
  unsigned short* wt_aa2 = wt_aa1 + 256 * 128;               // 256*256
  unsigned short* wt_aa3 = wt_aa2 + 256 * 256;               // 256*256
  unsigned short* wt_aa4 = wt_aa3 + 256 * 256;               // 32*256
  float* pool  = (float*)(wt_aa4 + 32 * 256);
  const size_t persist = (size_t)(pool - ws);

  // GNN-phase pool layout: agg(64N) | cnt(N) | rowptr(N+1) | cursor(N) | colidx(E) | bsum(256)
  const size_t gnn_need = 64 * N + N + (N + 1) + N + (size_t)Ee + 256;
  if (ws_floats < persist + gnn_need) return;
  const size_t pool_floats = ws_floats - persist;

  float* agg   = pool;
  int* cnt     = (int*)(pool + 64 * N);
  int* rowptr  = cnt + N;
  int* cursor  = rowptr + N + 1;
  int* colidx  = cursor + N;
  int* bsum    = colidx + Ee;

  const int* esrc = edge;
  const int* edst = edge + Ee;

  // ---- CSR build ----
  hipMemsetAsync(cnt, 0, N * sizeof(int), stream);
  k_degi<<<(Ee + 255) / 256, 256, 0, stream>>>(edst, cnt, Ee);
  k_rdeg<<<(Nn + 255) / 256, 256, 0, stream>>>(cnt, rdeg, Nn);
  const int nb = (Nn + 1023) / 1024;
  k_scan1<<<nb, 256, 0, stream>>>(cnt, cursor, bsum, Nn);   // cursor = partial excl
  k_scan2<<<1, 256, 0, stream>>>(bsum, nb);
  k_scan3<<<(Nn + 255) / 256, 256, 0, stream>>>(cursor, bsum, rowptr, cursor, Nn, Ee);
  k_fill<<<(Ee + 255) / 256, 256, 0, stream>>>(esrc, edst, cursor, colidx, Ee);

  // ---- weight prep ----
  k_wcat<<<48, 256, 0, stream>>>(Wl, Wr, Wcat);
  k_wt<<<(128 * 128 + 255) / 256, 256, 0, stream>>>(c1_w, wt_c1, 128, 7, 128, 128 * 128);
  k_wt<<<(128 * 128 + 255) / 256, 256, 0, stream>>>(c2_w, wt_c2, 128, 7, 128, 128 * 128);
  k_wt<<<(256 * 128 + 255) / 256, 256, 0, stream>>>(aa1_w, wt_aa1, 128, 7, 256, 256 * 128);
  k_wt<<<(256 * 256 + 255) / 256, 256, 0, stream>>>(aa2_w, wt_aa2, 256, 8, 256, 256 * 256);
  k_wt<<<(256 * 256 + 255) / 256, 256, 0, stream>>>(aa3_w, wt_aa3, 256, 8, 256, 256 * 256);
  k_wt<<<(32 * 256 + 255) / 256, 256, 0, stream>>>(aa4_w, wt_aa4, 256, 8, 20, 32 * 256);

  // ---- GNN phase (fp32 trunk) ----
  float* h = zn;
  for (int l = 0; l < 3; ++l) {
    const float* xi = (l == 0) ? x_res : (z + (size_t)(l - 1) * 64);
    int ldx = (l == 0) ? 64 : 192;
    hipMemsetAsync(stats, 0, 128 * sizeof(float), stream);
    k_gather<<<(Nn + 3) / 4, 256, 0, stream>>>(xi, ldx, rowptr, colidx, rdeg, agg, Nn);
    gemm(stream, agg, 64, xi, ldx, 64, nullptr, nullptr, nullptr,
         Wcat + (size_t)l * 8192, bl + l * 64, h, 64, Nn, 128, 64, 1);
    k_stats<<<1024, 256, 0, stream>>>(h, stats, Nn);
    k_statfin<<<1, 64, 0, stream>>>(stats, gn_ms + l * 64, Nn);
    k_norm<<<(Nn * 64) / 256, 256, 0, stream>>>(h, stats, gn_w + l * 64, gn_b + l * 64,
                                                z + (size_t)l * 64,
                                                (l > 0) ? (z + (size_t)(l - 1) * 64) : nullptr, Nn);
  }

  // ---- node-chunked: fp32 lin chain + bf16 MFMA annotation head ----
  size_t nc_max = (pool_floats / (2 * 256)) & ~(size_t)127;
  if (nc_max > N) nc_max = N;
  if (nc_max == 0) return;
  for (size_t r0 = 0; r0 < N; r0 += nc_max) {
    int nc = (int)((N - r0 < nc_max) ? (N - r0) : nc_max);
    float* R1 = pool;
    float* R2 = pool + nc_max * 256;
    const float* zrow = z + r0 * 192;
    float* znrow = zn + r0 * 64;
    const float* xrow = x_res + r0 * 64;
    // lin chain (fp32): dyt1 -> 256 -> 256 -> 64
    gemm(stream, zrow, 192, nullptr, 0, 192, dyt1_w, dyt1_b, dyt1_a,
         lin1_w, lin1_b, R1, 256, nc, 192, 256, 1);
    gemm(stream, R1, 256, nullptr, 0, 256, nullptr, nullptr, nullptr,
         lin2_w, lin2_b, R2, 256, nc, 256, 256, 1);
    gemm(stream, R2, 256, nullptr, 0, 256, nullptr, nullptr, nullptr,
         lin3_w, lin3_b, znrow, 64, nc, 256, 64, 1);
    k_rownorm<<<(nc * 64 + 255) / 256, 256, 0, stream>>>(znrow, xrow, dyt2_w, dyt2_b, dyt2_a, nc);
    // annotation head (bf16 MFMA)
    unsigned short* U1 = (unsigned short*)R1;
    unsigned short* U2 = (unsigned short*)R2;
    unsigned gx = (unsigned)((nc + 127) / 128);
    mgemm<8><<<dim3(gx, 2), 256, 0, stream>>>(xrow, 64, znrow, 64, 64, 0,
        adyt1_w, adyt1_b, adyt1_a, wt_aa1, aa1_b, U1, 256, 1, 1, nc, 128, 256);
    mgemm<8><<<dim3(gx, 2), 256, 0, stream>>>(U1, 256, U1, 256, 256, 1,
        nullptr, nullptr, nullptr, wt_aa2, aa2_b, U2, 256, 1, 1, nc, 256, 256);
    mgemm<8><<<dim3(gx, 2), 256, 0, stream>>>(U2, 256, U2, 256, 256, 1,
        nullptr, nullptr, nullptr, wt_aa3, aa3_b, U1, 256, 1, 1, nc, 256, 256);
    mgemm<2><<<dim3(gx, 1), 256, 0, stream>>>(U1, 256, U1, 256, 256, 1,
        adyt2_w, adyt2_b, adyt2_a, wt_aa4, aa4_b, R2, 32, 0, 0, nc, 256, 20);
    k_lsm<<<(nc + 255) / 256, 256, 0, stream>>>(R2, 32, (float*)d_out + r0 * 20, nc);
  }

  // ---- fused edge head ----
  float* eout = (float*)d_out + (size_t)Nn * 20;
  k_edge<<<(EPp + 127) / 128, 256, 0, stream>>>(zn, contact, contact + EPp,
      wt_c1, c1_b, wt_c2, c2_b, c3_w, c3_b, eout, EPp);
}

// Round 4
// 2796.245 us; speedup vs baseline: 4.2825x; 1.7872x over previous
//
#include <hip/hip_runtime.h>
#include <cstdint>
#include <cstddef>

// ---------------- problem constants ----------------
constexpr int Nn  = 200000;
constexpr int Ee  = 1600000;
constexpr int EPp = 1000000;

typedef __attribute__((ext_vector_type(8))) short bf8_t;
typedef __attribute__((ext_vector_type(4))) float f4_t;

__device__ inline unsigned short f2bf(float f) {
  union { float f; unsigned u; } v; v.f = f;
  unsigned r = v.u + 0x7FFFu + ((v.u >> 16) & 1u);
  return (unsigned short)(r >> 16);
}
__device__ inline float bf2f(unsigned short u) {
  union { unsigned u; float f; } v; v.u = ((unsigned)u) << 16;
  return v.f;
}
__device__ inline float gelu_f(float v) {
  return 0.5f * v * (1.0f + erff(v * 0.70710678118654752f));
}

// ---------------- degree / CSR build ----------------

__global__ __launch_bounds__(256) void k_degi(const int* __restrict__ dst,
                                              int* __restrict__ cnt, int E) {
  int i = blockIdx.x * 256 + threadIdx.x;
  if (i < E) atomicAdd(&cnt[dst[i]], 1);
}

__global__ __launch_bounds__(256) void k_rdeg(const int* __restrict__ cnt,
                                              float* __restrict__ rdeg, int n) {
  int i = blockIdx.x * 256 + threadIdx.x;
  if (i < n) rdeg[i] = 1.0f / (float)(cnt[i] > 1 ? cnt[i] : 1);
}

__global__ __launch_bounds__(256) void k_scan1(const int* __restrict__ in,
                                               int* __restrict__ out,
                                               int* __restrict__ bsum, int n) {
  __shared__ int sd[256];
  int t = threadIdx.x;
  int base = blockIdx.x * 1024 + t * 4;
  int v[4]; int ts = 0;
  #pragma unroll
  for (int j = 0; j < 4; ++j) { v[j] = (base + j < n) ? in[base + j] : 0; ts += v[j]; }
  sd[t] = ts; __syncthreads();
  for (int off = 1; off < 256; off <<= 1) {
    int x = (t >= off) ? sd[t - off] : 0;
    __syncthreads();
    sd[t] += x;
    __syncthreads();
  }
  int excl = sd[t] - ts;
  #pragma unroll
  for (int j = 0; j < 4; ++j) { if (base + j < n) out[base + j] = excl; excl += v[j]; }
  if (t == 255) bsum[blockIdx.x] = sd[255];
}

__global__ void k_scan2(int* bsum, int nb) {
  __shared__ int sd[256];
  int t = threadIdx.x;
  int v = (t < nb) ? bsum[t] : 0;
  sd[t] = v; __syncthreads();
  for (int off = 1; off < 256; off <<= 1) {
    int x = (t >= off) ? sd[t - off] : 0;
    __syncthreads();
    sd[t] += x;
    __syncthreads();
  }
  if (t < nb) bsum[t] = sd[t] - v;
}

__global__ __launch_bounds__(256) void k_scan3(const int* __restrict__ part,
                                               const int* __restrict__ bsum,
                                               int* __restrict__ rowptr,
                                               int* __restrict__ cursor,
                                               int n, int total) {
  int i = blockIdx.x * 256 + threadIdx.x;
  if (i == 0) rowptr[n] = total;
  if (i < n) { int v = part[i] + bsum[i >> 10]; rowptr[i] = v; cursor[i] = v; }
}

__global__ __launch_bounds__(256) void k_fill(const int* __restrict__ src,
                                              const int* __restrict__ dst,
                                              int* __restrict__ cursor,
                                              int* __restrict__ colidx, int E) {
  int e = blockIdx.x * 256 + threadIdx.x;
  if (e >= E) return;
  int pos = atomicAdd(&cursor[dst[e]], 1);
  colidx[pos] = src[e];
}

// gather-mean over bf16 features: one wave per node, 4 groups of 16 lanes.
// x rows are bf16 with stride ldx (shorts); output agg bf16 [n,64].
__global__ __launch_bounds__(256) void k_gather(const unsigned short* __restrict__ x, int ldx,
                                                const int* __restrict__ rowptr,
                                                const int* __restrict__ colidx,
                                                const float* __restrict__ rdeg,
                                                unsigned short* __restrict__ agg, int n) {
  int wave = threadIdx.x >> 6, lane = threadIdx.x & 63;
  int node = blockIdx.x * 4 + wave;
  if (node >= n) return;
  int grp = lane >> 4, c = (lane & 15) * 4;
  int r0 = rowptr[node], r1 = rowptr[node + 1];
  float sx = 0.f, sy = 0.f, sz = 0.f, sw = 0.f;
  for (int j = r0 + grp; j < r1; j += 4) {
    const ushort4 v = *(const ushort4*)(x + (size_t)colidx[j] * ldx + c);
    sx += bf2f(v.x); sy += bf2f(v.y); sz += bf2f(v.z); sw += bf2f(v.w);
  }
  sx += __shfl_xor(sx, 16, 64); sx += __shfl_xor(sx, 32, 64);
  sy += __shfl_xor(sy, 16, 64); sy += __shfl_xor(sy, 32, 64);
  sz += __shfl_xor(sz, 16, 64); sz += __shfl_xor(sz, 32, 64);
  sw += __shfl_xor(sw, 16, 64); sw += __shfl_xor(sw, 32, 64);
  if (grp == 0) {
    float r = rdeg[node];
    ushort4 o;
    o.x = f2bf(sx * r); o.y = f2bf(sy * r); o.z = f2bf(sz * r); o.w = f2bf(sw * r);
    *(ushort4*)(agg + (size_t)node * 64 + c) = o;
  }
}

// ---------------- misc small kernels ----------------

__global__ __launch_bounds__(256) void k_cvt(const float* __restrict__ in,
                                             unsigned short* __restrict__ out, int n) {
  int i = blockIdx.x * 256 + threadIdx.x;
  if (i < n) out[i] = f2bf(in[i]);
}

// transpose + cvt weights: W[K][N] fp32 -> Wt[Npad][K] bf16 (zero-fill n>=N)
__global__ __launch_bounds__(256) void k_wt2(const float* __restrict__ W,
                                             unsigned short* __restrict__ Wt,
                                             int K, int N, int total) {
  int i = blockIdx.x * 256 + threadIdx.x;
  if (i >= total) return;
  int n = i / K, k = i - n * K;
  float v = (n < N) ? W[(size_t)k * N + n] : 0.f;
  Wt[i] = f2bf(v);
}

// SAGE weights: Wt[l][n][k] = (k<64 ? Wl[l][k][n] : Wr[l][k-64][n])  (64x128 per layer)
__global__ __launch_bounds__(256) void k_wtsage(const float* __restrict__ Wl,
                                                const float* __restrict__ Wr,
                                                unsigned short* __restrict__ Wt) {
  int i = blockIdx.x * 256 + threadIdx.x;
  if (i >= 3 * 64 * 128) return;
  int l = i >> 13, r = i & 8191, n = r >> 7, k = r & 127;
  float v = (k < 64) ? Wl[l * 4096 + k * 64 + n] : Wr[l * 4096 + (k - 64) * 64 + n];
  Wt[i] = f2bf(v);
}

__global__ __launch_bounds__(256) void k_stats(const float* __restrict__ h,
                                               float* __restrict__ stats, int n) {
  int lane = threadIdx.x & 63, grp = threadIdx.x >> 6;
  float s = 0.f, s2 = 0.f;
  for (int r = blockIdx.x * 4 + grp; r < n; r += gridDim.x * 4) {
    float v = h[(size_t)r * 64 + lane];
    s += v; s2 += v * v;
  }
  __shared__ float l1[4][64], l2[4][64];
  l1[grp][lane] = s; l2[grp][lane] = s2;
  __syncthreads();
  if (grp == 0) {
    s  = l1[0][lane] + l1[1][lane] + l1[2][lane] + l1[3][lane];
    s2 = l2[0][lane] + l2[1][lane] + l2[2][lane] + l2[3][lane];
    atomicAdd(&stats[lane], s);
    atomicAdd(&stats[64 + lane], s2);
  }
}

__global__ void k_statfin(float* stats, const float* __restrict__ ms_, int n) {
  int d = threadIdx.x;
  if (d < 64) {
    float invn = 1.0f / (float)n;
    float m  = stats[d] * invn;
    float e2 = stats[64 + d] * invn;
    float ms = ms_[d];
    float var = e2 - (2.0f * ms - ms * ms) * m * m;
    stats[128 + d] = ms * m;
    stats[192 + d] = rsqrtf(var + 1e-5f);
  }
}

// graph_norm apply + residual; write bf16 z column (row stride 192 shorts)
__global__ __launch_bounds__(256) void k_norm(const float* __restrict__ h,
                                              const float* __restrict__ stats,
                                              const float* __restrict__ w,
                                              const float* __restrict__ b,
                                              unsigned short* __restrict__ zcol,
                                              const unsigned short* __restrict__ prev, int n) {
  int i = blockIdx.x * 256 + threadIdx.x;
  if (i >= n * 64) return;
  int r = i >> 6, d = i & 63;
  float v = (h[i] - stats[128 + d]) * stats[192 + d] * w[d] + b[d];
  if (prev) v += bf2f(prev[(size_t)r * 192 + d]);
  zcol[(size_t)r * 192 + d] = f2bf(v);
}

// zn = normalize(dyt2(zn) + x_res); writes fp32 zn and bf16 shadow
__global__ __launch_bounds__(256) void k_rownorm(float* __restrict__ zn,
                                                 unsigned short* __restrict__ zn_bf,
                                                 const float* __restrict__ xres,
                                                 const float* __restrict__ w,
                                                 const float* __restrict__ b,
                                                 const float* __restrict__ a_, int n) {
  int i = blockIdx.x * 256 + threadIdx.x;
  if (i >= n * 64) return;
  int d = i & 63;
  float al = a_[0];
  float v = w[d] * tanhf(al * zn[i]) + b[d] + xres[i];
  float s = v * v;
  #pragma unroll
  for (int o = 32; o; o >>= 1) s += __shfl_xor(s, o, 64);
  float r = v / (sqrtf(s) + 1e-10f);
  zn[i] = r;
  zn_bf[i] = f2bf(r);
}

__global__ __launch_bounds__(256) void k_lsm(const float* __restrict__ in, int ld,
                                             float* __restrict__ out, int n) {
  int r = blockIdx.x * 256 + threadIdx.x;
  if (r >= n) return;
  const float* p = in + (size_t)r * ld;
  float m = -1e30f;
  #pragma unroll
  for (int j = 0; j < 20; ++j) m = fmaxf(m, p[j]);
  float s = 0.f;
  #pragma unroll
  for (int j = 0; j < 20; ++j) s += expf(p[j] - m);
  float ls = logf(s) + m;
  float* q = out + (size_t)r * 20;
  #pragma unroll
  for (int j = 0; j < 20; ++j) q[j] = p[j] - ls;
}

// ---------------- generic bf16 MFMA GEMM (barrier-free) ----------------
// C = act( concatA[M,K] @ Wt^T + bias ); Wt is [Npad][K] bf16 (n-major).
// A fp32 or bf16 (a_bf16 applies to both A1/A2), optional DynamicTanh on load.
// Block: 256 thr / 4 waves, 128 rows per block, NT n-tiles of 16 per grid.y.
template <int NT>
__global__ __launch_bounds__(256) void mgemm(
    const void* __restrict__ A1, int lda1,
    const void* __restrict__ A2, int lda2, int K1, int a_bf16,
    const float* __restrict__ dytw, const float* __restrict__ dytb,
    const float* __restrict__ dyta,
    const unsigned short* __restrict__ Wt,
    const float* __restrict__ bias,
    void* __restrict__ Cout, int ldc, int c_bf16, int act,
    int M, int K, int N) {
  int lane = threadIdx.x & 63, wave = threadIdx.x >> 6;
  int quad = lane >> 4, col = lane & 15;
  int row0 = blockIdx.x * 128 + wave * 32;
  int n_base = blockIdx.y * NT * 16;

  f4_t acc[2][NT];
  #pragma unroll
  for (int mt = 0; mt < 2; ++mt)
    #pragma unroll
    for (int nt = 0; nt < NT; ++nt) acc[mt][nt] = (f4_t)0.f;

  int gm[2];
  gm[0] = row0 + col;      if (gm[0] >= M) gm[0] = M - 1;
  gm[1] = row0 + 16 + col; if (gm[1] >= M) gm[1] = M - 1;
  float alpha = dytw ? dyta[0] : 0.f;

  for (int kc0 = 0; kc0 < K; kc0 += 32) {
    int kc = kc0 + quad * 8;
    union { bf8_t v; unsigned short u[8]; } a[2];
    #pragma unroll
    for (int mt = 0; mt < 2; ++mt) {
      const void* src; size_t off;
      if (kc < K1) { src = A1; off = (size_t)gm[mt] * lda1 + kc; }
      else         { src = A2; off = (size_t)gm[mt] * lda2 + kc - K1; }
      if (a_bf16) {
        a[mt].v = *(const bf8_t*)((const unsigned short*)src + off);
        if (dytw) {
          #pragma unroll
          for (int j = 0; j < 8; ++j) {
            float f = bf2f((unsigned short)a[mt].u[j]);
            f = dytw[kc + j] * tanhf(alpha * f) + dytb[kc + j];
            a[mt].u[j] = f2bf(f);
          }
        }
      } else {
        const float* p = (const float*)src + off;
        float4 f0 = *(const float4*)p;
        float4 f1 = *(const float4*)(p + 4);
        float ff[8] = {f0.x, f0.y, f0.z, f0.w, f1.x, f1.y, f1.z, f1.w};
        if (dytw) {
          #pragma unroll
          for (int j = 0; j < 8; ++j)
            ff[j] = dytw[kc + j] * tanhf(alpha * ff[j]) + dytb[kc + j];
        }
        #pragma unroll
        for (int j = 0; j < 8; ++j) a[mt].u[j] = f2bf(ff[j]);
      }
    }
    #pragma unroll
    for (int nt = 0; nt < NT; ++nt) {
      bf8_t b = *(const bf8_t*)(Wt + (size_t)(n_base + nt * 16 + col) * K + kc);
      acc[0][nt] = __builtin_amdgcn_mfma_f32_16x16x32_bf16(a[0].v, b, acc[0][nt], 0, 0, 0);
      acc[1][nt] = __builtin_amdgcn_mfma_f32_16x16x32_bf16(a[1].v, b, acc[1][nt], 0, 0, 0);
    }
  }

  #pragma unroll
  for (int nt = 0; nt < NT; ++nt) {
    int n = n_base + nt * 16 + col;
    float bs = (bias && n < N) ? bias[n] : 0.f;
    #pragma unroll
    for (int mt = 0; mt < 2; ++mt)
      #pragma unroll
      for (int r = 0; r < 4; ++r) {
        int row = row0 + mt * 16 + quad * 4 + r;
        if (row >= M || n >= N) continue;
        float v = acc[mt][nt][r] + bs;
        if (act) v = gelu_f(v);
        if (c_bf16) ((unsigned short*)Cout)[(size_t)row * ldc + n] = f2bf(v);
        else        ((float*)Cout)[(size_t)row * ldc + n] = v;
      }
  }
}

// ---------------- fused edge head: c1+c2+c3+sigmoid (bf16 gather) ----------------
__global__ __launch_bounds__(256) void k_edge(
    const unsigned short* __restrict__ zn_bf,
    const int* __restrict__ ci, const int* __restrict__ cj,
    const unsigned short* __restrict__ w1t, const float* __restrict__ b1,
    const unsigned short* __restrict__ w2t, const float* __restrict__ b2,
    const float* __restrict__ w3, const float* __restrict__ b3,
    float* __restrict__ out, int M) {
  __shared__ unsigned short h1[4][32][136];
  int lane = threadIdx.x & 63, wave = threadIdx.x >> 6;
  int quad = lane >> 4, col = lane & 15;
  int row0 = blockIdx.x * 128 + wave * 32;

  f4_t acc[2][8];
  #pragma unroll
  for (int mt = 0; mt < 2; ++mt)
    #pragma unroll
    for (int nt = 0; nt < 8; ++nt) acc[mt][nt] = (f4_t)0.f;

  const unsigned short* ap[2][2];
  #pragma unroll
  for (int mt = 0; mt < 2; ++mt) {
    int r = row0 + mt * 16 + col;
    if (r >= M) r = M - 1;
    ap[mt][0] = zn_bf + (size_t)ci[r] * 64;
    ap[mt][1] = zn_bf + (size_t)cj[r] * 64;
  }

  // gather all A fragments up front (8 x 16B loads in flight)
  bf8_t afrag[2][4];
  #pragma unroll
  for (int s = 0; s < 4; ++s) {
    int kc = (s & 1) * 32 + quad * 8;
    #pragma unroll
    for (int mt = 0; mt < 2; ++mt)
      afrag[mt][s] = *(const bf8_t*)(ap[mt][s >> 1] + kc);
  }

  // ---- c1 ----
  #pragma unroll
  for (int s = 0; s < 4; ++s) {
    int kf = s * 32 + quad * 8;
    #pragma unroll
    for (int nt = 0; nt < 8; ++nt) {
      bf8_t b = *(const bf8_t*)(w1t + (size_t)(nt * 16 + col) * 128 + kf);
      acc[0][nt] = __builtin_amdgcn_mfma_f32_16x16x32_bf16(afrag[0][s], b, acc[0][nt], 0, 0, 0);
      acc[1][nt] = __builtin_amdgcn_mfma_f32_16x16x32_bf16(afrag[1][s], b, acc[1][nt], 0, 0, 0);
    }
  }

  // bias + gelu -> h1 (LDS, bf16): layout hop C/D -> A
  #pragma unroll
  for (int nt = 0; nt < 8; ++nt) {
    float bs = b1[nt * 16 + col];
    #pragma unroll
    for (int mt = 0; mt < 2; ++mt)
      #pragma unroll
      for (int r = 0; r < 4; ++r) {
        float v = gelu_f(acc[mt][nt][r] + bs);
        h1[wave][mt * 16 + quad * 4 + r][nt * 16 + col] = f2bf(v);
      }
  }
  __syncthreads();

  // ---- c2 (+ fused c3 dot) ----
  #pragma unroll
  for (int mt = 0; mt < 2; ++mt)
    #pragma unroll
    for (int nt = 0; nt < 8; ++nt) acc[mt][nt] = (f4_t)0.f;

  #pragma unroll
  for (int s = 0; s < 4; ++s) {
    int kc = s * 32 + quad * 8;
    bf8_t a0 = *(const bf8_t*)&h1[wave][col][kc];
    bf8_t a1 = *(const bf8_t*)&h1[wave][16 + col][kc];
    #pragma unroll
    for (int nt = 0; nt < 8; ++nt) {
      bf8_t b = *(const bf8_t*)(w2t + (size_t)(nt * 16 + col) * 128 + kc);
      acc[0][nt] = __builtin_amdgcn_mfma_f32_16x16x32_bf16(a0, b, acc[0][nt], 0, 0, 0);
      acc[1][nt] = __builtin_amdgcn_mfma_f32_16x16x32_bf16(a1, b, acc[1][nt], 0, 0, 0);
    }
  }

  float p[2][4] = {{0.f,0.f,0.f,0.f},{0.f,0.f,0.f,0.f}};
  #pragma unroll
  for (int nt = 0; nt < 8; ++nt) {
    float bs = b2[nt * 16 + col];
    float wv = w3[nt * 16 + col];
    #pragma unroll
    for (int mt = 0; mt < 2; ++mt)
      #pragma unroll
      for (int r = 0; r < 4; ++r)
        p[mt][r] += gelu_f(acc[mt][nt][r] + bs) * wv;
  }
  float b3v = b3[0];
  #pragma unroll
  for (int mt = 0; mt < 2; ++mt)
    #pragma unroll
    for (int r = 0; r < 4; ++r) {
      float s = p[mt][r];
      s += __shfl_xor(s, 1, 64);
      s += __shfl_xor(s, 2, 64);
      s += __shfl_xor(s, 4, 64);
      s += __shfl_xor(s, 8, 64);
      p[mt][r] = s;
    }
  if (col == 0) {
    #pragma unroll
    for (int mt = 0; mt < 2; ++mt)
      #pragma unroll
      for (int r = 0; r < 4; ++r) {
        int row = row0 + mt * 16 + quad * 4 + r;
        if (row < M) out[row] = 1.0f / (1.0f + expf(-(p[mt][r] + b3v)));
      }
  }
}

// ---------------- launcher ----------------
extern "C" void kernel_launch(void* const* d_in, const int* in_sizes, int n_in,
                              void* d_out, int out_size, void* d_ws, size_t ws_size,
                              hipStream_t stream) {
  const float* x_res  = (const float*)d_in[0];
  const float* Wl     = (const float*)d_in[1];
  const float* bl     = (const float*)d_in[2];
  const float* Wr     = (const float*)d_in[3];
  const float* gn_w   = (const float*)d_in[4];
  const float* gn_b   = (const float*)d_in[5];
  const float* gn_ms  = (const float*)d_in[6];
  const float* dyt1_w = (const float*)d_in[7];
  const float* dyt1_b = (const float*)d_in[8];
  const float* dyt1_a = (const float*)d_in[9];
  const float* lin1_w = (const float*)d_in[10];
  const float* lin1_b = (const float*)d_in[11];
  const float* lin2_w = (const float*)d_in[12];
  const float* lin2_b = (const float*)d_in[13];
  const float* lin3_w = (const float*)d_in[14];
  const float* lin3_b = (const float*)d_in[15];
  const float* dyt2_w = (const float*)d_in[16];
  const float* dyt2_b = (const float*)d_in[17];
  const float* dyt2_a = (const float*)d_in[18];
  const float* adyt1_w = (const float*)d_in[19];
  const float* adyt1_b = (const float*)d_in[20];
  const float* adyt1_a = (const float*)d_in[21];
  const float* aa1_w  = (const float*)d_in[22];
  const float* aa1_b  = (const float*)d_in[23];
  const float* aa2_w  = (const float*)d_in[24];
  const float* aa2_b  = (const float*)d_in[25];
  const float* aa3_w  = (const float*)d_in[26];
  const float* aa3_b  = (const float*)d_in[27];
  const float* adyt2_w = (const float*)d_in[28];
  const float* adyt2_b = (const float*)d_in[29];
  const float* adyt2_a = (const float*)d_in[30];
  const float* aa4_w  = (const float*)d_in[31];
  const float* aa4_b  = (const float*)d_in[32];
  const float* c1_w   = (const float*)d_in[33];
  const float* c1_b   = (const float*)d_in[34];
  const float* c2_w   = (const float*)d_in[35];
  const float* c2_b   = (const float*)d_in[36];
  const float* c3_w   = (const float*)d_in[37];
  const float* c3_b   = (const float*)d_in[38];
  const int*   edge   = (const int*)d_in[39];
  const int*   contact = (const int*)d_in[40];

  const size_t N = (size_t)Nn;
  const size_t ws_floats = ws_size / 4;

  // ---- persistent region (floats) ----
  float* ws    = (float*)d_ws;
  float* rdeg  = ws;                                  // N
  float* zn    = rdeg + N;                            // 64N fp32 (h during GNN)
  unsigned short* z_bf  = (unsigned short*)(zn + 64 * N);   // 192N shorts (96N fl)
  unsigned short* zn_bf = z_bf + 192 * N;                   // 64N shorts (32N fl) — xb during GNN
  float* stats = (float*)(zn_bf + 64 * N);            // 256
  unsigned short* wt_sage = (unsigned short*)(stats + 256); // 3*64*128
  unsigned short* wt_lin1 = wt_sage + 3 * 64 * 128;   // 256*192
  unsigned short* wt_lin2 = wt_lin1 + 256 * 192;      // 256*256
  unsigned short* wt_lin3 = wt_lin2 + 256 * 256;      // 64*256
  unsigned short* wt_aa1  = wt_lin3 + 64 * 256;       // 256*128
  unsigned short* wt_aa2  = wt_aa1 + 256 * 128;       // 256*256
  unsigned short* wt_aa3  = wt_aa2 + 256 * 256;       // 256*256
  unsigned short* wt_aa4  = wt_aa3 + 256 * 256;       // 32*256
  unsigned short* wt_c1   = wt_aa4 + 32 * 256;        // 128*128
  unsigned short* wt_c2   = wt_c1 + 128 * 128;        // 128*128
  unsigned short* wt_end  = wt_c2 + 128 * 128;
  float* pool  = (float*)((((uintptr_t)wt_end + 15) & ~(uintptr_t)15));
  const size_t persist = (size_t)(pool - ws);

  // GNN pool: agg_bf(32N fl) | cnt(N) | rowptr(N+1) | cursor(N) | colidx(E) | bsum(256)
  const size_t gnn_need = 32 * N + N + (N + 1) + N + (size_t)Ee + 256;
  if (ws_floats < persist + gnn_need) return;
  const size_t pool_floats = ws_floats - persist;

  unsigned short* agg_bf = (unsigned short*)pool;     // [N,64] bf16
  int* cnt     = (int*)(pool + 32 * N);
  int* rowptr  = cnt + N;
  int* cursor  = rowptr + N + 1;
  int* colidx  = cursor + N;
  int* bsum    = colidx + Ee;

  const int* esrc = edge;
  const int* edst = edge + Ee;

  // ---- CSR build ----
  hipMemsetAsync(cnt, 0, N * sizeof(int), stream);
  k_degi<<<(Ee + 255) / 256, 256, 0, stream>>>(edst, cnt, Ee);
  k_rdeg<<<(Nn + 255) / 256, 256, 0, stream>>>(cnt, rdeg, Nn);
  const int nb = (Nn + 1023) / 1024;
  k_scan1<<<nb, 256, 0, stream>>>(cnt, cursor, bsum, Nn);
  k_scan2<<<1, 256, 0, stream>>>(bsum, nb);
  k_scan3<<<(Nn + 255) / 256, 256, 0, stream>>>(cursor, bsum, rowptr, cursor, Nn, Ee);
  k_fill<<<(Ee + 255) / 256, 256, 0, stream>>>(esrc, edst, cursor, colidx, Ee);

  // ---- weight prep ----
  k_wtsage<<<(3 * 64 * 128 + 255) / 256, 256, 0, stream>>>(Wl, Wr, wt_sage);
  k_wt2<<<(256 * 192 + 255) / 256, 256, 0, stream>>>(lin1_w, wt_lin1, 192, 256, 256 * 192);
  k_wt2<<<(256 * 256 + 255) / 256, 256, 0, stream>>>(lin2_w, wt_lin2, 256, 256, 256 * 256);
  k_wt2<<<(64 * 256 + 255) / 256, 256, 0, stream>>>(lin3_w, wt_lin3, 256, 64, 64 * 256);
  k_wt2<<<(256 * 128 + 255) / 256, 256, 0, stream>>>(aa1_w, wt_aa1, 128, 256, 256 * 128);
  k_wt2<<<(256 * 256 + 255) / 256, 256, 0, stream>>>(aa2_w, wt_aa2, 256, 256, 256 * 256);
  k_wt2<<<(256 * 256 + 255) / 256, 256, 0, stream>>>(aa3_w, wt_aa3, 256, 256, 256 * 256);
  k_wt2<<<(32 * 256 + 255) / 256, 256, 0, stream>>>(aa4_w, wt_aa4, 256, 20, 32 * 256);
  k_wt2<<<(128 * 128 + 255) / 256, 256, 0, stream>>>(c1_w, wt_c1, 128, 128, 128 * 128);
  k_wt2<<<(128 * 128 + 255) / 256, 256, 0, stream>>>(c2_w, wt_c2, 128, 128, 128 * 128);

  // xb = bf16(x_res) in zn_bf slot (consumed by layer-0 gather + SAGE A2)
  k_cvt<<<(int)((N * 64 + 255) / 256), 256, 0, stream>>>(x_res, zn_bf, (int)(N * 64));

  // ---- GNN phase ----
  float* h = zn;
  for (int l = 0; l < 3; ++l) {
    const unsigned short* xi = (l == 0) ? zn_bf : (z_bf + (size_t)(l - 1) * 64);
    int ldx = (l == 0) ? 64 : 192;
    hipMemsetAsync(stats, 0, 128 * sizeof(float), stream);
    k_gather<<<(Nn + 3) / 4, 256, 0, stream>>>(xi, ldx, rowptr, colidx, rdeg, agg_bf, Nn);
    // h = gelu([agg, x] @ Wsage^T + bl)
    mgemm<4><<<dim3((Nn + 127) / 128, 1), 256, 0, stream>>>(
        agg_bf, 64, xi, ldx, 64, 1, nullptr, nullptr, nullptr,
        wt_sage + (size_t)l * 8192, bl + l * 64, h, 64, 0, 1, Nn, 128, 64);
    k_stats<<<1024, 256, 0, stream>>>(h, stats, Nn);
    k_statfin<<<1, 64, 0, stream>>>(stats, gn_ms + l * 64, Nn);
    k_norm<<<(Nn * 64) / 256, 256, 0, stream>>>(h, stats, gn_w + l * 64, gn_b + l * 64,
                                                z_bf + (size_t)l * 64,
                                                (l > 0) ? (z_bf + (size_t)(l - 1) * 64) : nullptr, Nn);
  }

  // ---- node-chunked: bf16 MFMA lin chain + annotation head ----
  size_t nc_max = (pool_floats / 256) & ~(size_t)127;  // two bf16 [nc,256] buffers
  if (nc_max > N) nc_max = N;
  if (nc_max == 0) return;
  for (size_t r0 = 0; r0 < N; r0 += nc_max) {
    int nc = (int)((N - r0 < nc_max) ? (N - r0) : nc_max);
    unsigned short* U1 = (unsigned short*)pool;
    unsigned short* U2 = U1 + nc_max * 256;
    const unsigned short* zrow = z_bf + r0 * 192;
    float* znrow = zn + r0 * 64;
    unsigned short* znbrow = zn_bf + r0 * 64;
    const float* xrow = x_res + r0 * 64;
    unsigned gx = (unsigned)((nc + 127) / 128);
    // lin chain: dyt1 -> 256 -> 256 -> 64 (gelu each)
    mgemm<8><<<dim3(gx, 2), 256, 0, stream>>>(zrow, 192, zrow, 192, 192, 1,
        dyt1_w, dyt1_b, dyt1_a, wt_lin1, lin1_b, U1, 256, 1, 1, nc, 192, 256);
    mgemm<8><<<dim3(gx, 2), 256, 0, stream>>>(U1, 256, U1, 256, 256, 1,
        nullptr, nullptr, nullptr, wt_lin2, lin2_b, U2, 256, 1, 1, nc, 256, 256);
    mgemm<4><<<dim3(gx, 1), 256, 0, stream>>>(U2, 256, U2, 256, 256, 1,
        nullptr, nullptr, nullptr, wt_lin3, lin3_b, znrow, 64, 0, 1, nc, 256, 64);
    k_rownorm<<<(nc * 64 + 255) / 256, 256, 0, stream>>>(znrow, znbrow, xrow,
                                                         dyt2_w, dyt2_b, dyt2_a, nc);
    // annotation head
    mgemm<8><<<dim3(gx, 2), 256, 0, stream>>>(xrow, 64, znrow, 64, 64, 0,
        adyt1_w, adyt1_b, adyt1_a, wt_aa1, aa1_b, U1, 256, 1, 1, nc, 128, 256);
    mgemm<8><<<dim3(gx, 2), 256, 0, stream>>>(U1, 256, U1, 256, 256, 1,
        nullptr, nullptr, nullptr, wt_aa2, aa2_b, U2, 256, 1, 1, nc, 256, 256);
    mgemm<8><<<dim3(gx, 2), 256, 0, stream>>>(U2, 256, U2, 256, 256, 1,
        nullptr, nullptr, nullptr, wt_aa3, aa3_b, U1, 256, 1, 1, nc, 256, 256);
    float* R2f = (float*)U2;  // [nc,32] fp32 logits
    mgemm<2><<<dim3(gx, 1), 256, 0, stream>>>(U1, 256, U1, 256, 256, 1,
        adyt2_w, adyt2_b, adyt2_a, wt_aa4, aa4_b, R2f, 32, 0, 0, nc, 256, 20);
    k_lsm<<<(nc + 255) / 256, 256, 0, stream>>>(R2f, 32, (float*)d_out + r0 * 20, nc);
  }

  // ---- fused edge head ----
  float* eout = (float*)d_out + (size_t)Nn * 20;
  k_edge<<<(EPp + 127) / 128, 256, 0, stream>>>(zn_bf, contact, contact + EPp,
      wt_c1, c1_b, wt_c2, c2_b, c3_w, c3_b, eout, EPp);
}